// Round 2
// baseline (59.227 us; speedup 1.0000x reference)
//
#include <hip/hip_runtime.h>

#define DD 128
#define HH 160
#define WW 128
#define BB 4
#define HW  (HH * WW)
#define DHW (DD * HH * WW)

typedef float vfloat2 __attribute__((ext_vector_type(2)));

__global__ __launch_bounds__(256)
void st_affine_kernel(const float* __restrict__ src,
                      const float* __restrict__ aff,
                      float* __restrict__ out) {
    // Block = 256 threads = 4 rows; each thread does 2 consecutive x.
    const int b   = blockIdx.z;
    const int z   = blockIdx.y;
    const int tid = threadIdx.x;
    const int y   = blockIdx.x * 4 + (tid >> 6);
    const int x   = (tid & 63) << 1;

    const float* A = aff + b * 12;  // b is uniform -> uniform loads
    const float cD = (float)DD / (float)(DD - 1);
    const float cH = (float)HH / (float)(HH - 1);
    const float cW = (float)WW / (float)(WW - 1);

    const float fz = (float)z, fy = (float)y, fx = (float)x;

    // loc = A @ [z, y, x, 1]; i = loc * S/(S-1) - 0.5  (algebraic reduction
    // of the reference normalize/unnormalize chain; diff ~1e-5 in coords)
    float lz = A[0] * fz + A[1] * fy + A[2]  * fx + A[3];
    float ly = A[4] * fz + A[5] * fy + A[6]  * fx + A[7];
    float lx = A[8] * fz + A[9] * fy + A[10] * fx + A[11];

    float iz0 = lz * cD - 0.5f;
    float iy0 = ly * cH - 0.5f;
    float ix0 = lx * cW - 0.5f;
    // per-x-step coordinate deltas
    const float ddz = A[2]  * cD;
    const float ddy = A[6]  * cH;
    const float ddx = A[10] * cW;

    const float* s = src + b * DHW;
    float res[2];

#pragma unroll
    for (int e = 0; e < 2; ++e) {
        float ix = ix0 + (float)e * ddx;
        float iy = iy0 + (float)e * ddy;
        float iz = iz0 + (float)e * ddz;

        ix = fminf(fmaxf(ix, 0.0f), (float)(WW - 1));
        iy = fminf(fmaxf(iy, 0.0f), (float)(HH - 1));
        iz = fminf(fmaxf(iz, 0.0f), (float)(DD - 1));

        float x0f = floorf(ix), y0f = floorf(iy), z0f = floorf(iz);
        float wx = ix - x0f, wy = iy - y0f, wz = iz - z0f;

        int x0 = (int)x0f, y0 = (int)y0f, z0 = (int)z0f;
        int x1 = min(x0 + 1, WW - 1);
        int y1 = min(y0 + 1, HH - 1);
        int z1 = min(z0 + 1, DD - 1);

        int z0w = z0 * HW, z1w = z1 * HW;
        int y0w = y0 << 7, y1w = y1 << 7;  // *WW (WW=128)

        int zy00 = z0w + y0w;
        int zy01 = z0w + y1w;
        int zy10 = z1w + y0w;
        int zy11 = z1w + y1w;

        float c000 = s[zy00 + x0], c001 = s[zy00 + x1];
        float c010 = s[zy01 + x0], c011 = s[zy01 + x1];
        float c100 = s[zy10 + x0], c101 = s[zy10 + x1];
        float c110 = s[zy11 + x0], c111 = s[zy11 + x1];

        float c00 = c000 + (c001 - c000) * wx;
        float c01 = c010 + (c011 - c010) * wx;
        float c10 = c100 + (c101 - c100) * wx;
        float c11 = c110 + (c111 - c110) * wx;
        float c0  = c00 + (c01 - c00) * wy;
        float c1  = c10 + (c11 - c10) * wy;
        res[e]    = c0 + (c1 - c0) * wz;
    }

    vfloat2 o;
    o.x = res[0];
    o.y = res[1];
    vfloat2* dst = (vfloat2*)(out + (size_t)((b * DD + z) * HH + y) * WW + x);
    __builtin_nontemporal_store(o, dst);
}

extern "C" void kernel_launch(void* const* d_in, const int* in_sizes, int n_in,
                              void* d_out, int out_size, void* d_ws, size_t ws_size,
                              hipStream_t stream) {
    const float* src = (const float*)d_in[0];
    const float* aff = (const float*)d_in[1];
    float* out = (float*)d_out;

    dim3 grid(HH / 4, DD, BB);   // 40 x 128 x 4
    dim3 block(256);
    st_affine_kernel<<<grid, block, 0, stream>>>(src, aff, out);
}

// Round 3
// 30.467 us; speedup vs baseline: 1.9439x; 1.9439x over previous
//
#include <hip/hip_runtime.h>

#define DD 128
#define HH 160
#define WW 128
#define BB 4
#define HW  (HH * WW)
#define DHW (DD * HH * WW)

// 8-byte vector load with only 4-byte alignment guarantee (x0 has arbitrary
// parity). gfx9+ supports unaligned global access; backend emits dwordx2.
typedef float f2 __attribute__((ext_vector_type(2), aligned(4)));

__global__ __launch_bounds__(256)
void st_affine_kernel(const float* __restrict__ src,
                      const float* __restrict__ aff,
                      float* __restrict__ out) {
    const int b   = blockIdx.z;
    const int z   = blockIdx.y;
    const int tid = threadIdx.x;
    const int y   = blockIdx.x * 2 + (tid >> 7);
    const int x   = tid & 127;          // lanes stride-1 in x

    const float* A = aff + b * 12;      // b uniform -> scalar loads
    const float cD = (float)DD / (float)(DD - 1);
    const float cH = (float)HH / (float)(HH - 1);
    const float cW = (float)WW / (float)(WW - 1);

    const float fz = (float)z, fy = (float)y, fx = (float)x;

    // loc = A @ [z,y,x,1];  i = loc * S/(S-1) - 0.5  (algebraic reduction of
    // the reference normalize/unnormalize chain; coord diff ~1e-5)
    float lz = fmaf(A[0], fz, fmaf(A[1], fy, fmaf(A[2],  fx, A[3])));
    float ly = fmaf(A[4], fz, fmaf(A[5], fy, fmaf(A[6],  fx, A[7])));
    float lx = fmaf(A[8], fz, fmaf(A[9], fy, fmaf(A[10], fx, A[11])));

    float iz = fmaf(lz, cD, -0.5f);
    float iy = fmaf(ly, cH, -0.5f);
    float ix = fmaf(lx, cW, -0.5f);

    // border clamp
    ix = fminf(fmaxf(ix, 0.0f), (float)(WW - 1));
    iy = fminf(fmaxf(iy, 0.0f), (float)(HH - 1));
    iz = fminf(fmaxf(iz, 0.0f), (float)(DD - 1));

    float x0f = floorf(ix), y0f = floorf(iy), z0f = floorf(iz);
    float wy = iy - y0f, wz = iz - z0f;

    int x0 = (int)x0f, y0 = (int)y0f, z0 = (int)z0f;
    // shift base so [x0c, x0c+1] is always in-row; adjust weight accordingly.
    // When x0 == W-1 (wx==0): x0c = W-2, wx' = 1.0 -> exactly v[W-1].
    int x0c = min(x0, WW - 2);
    float wx = (ix - x0f) + (float)(x0 - x0c);

    int y1 = min(y0 + 1, HH - 1);
    int z1 = min(z0 + 1, DD - 1);

    const float* s = src + b * DHW;
    int z0w = z0 * HW, z1w = z1 * HW;
    int y0w = y0 << 7, y1w = y1 << 7;   // * WW (=128)

    f2 v00 = *(const f2*)(s + (z0w + y0w + x0c));
    f2 v01 = *(const f2*)(s + (z0w + y1w + x0c));
    f2 v10 = *(const f2*)(s + (z1w + y0w + x0c));
    f2 v11 = *(const f2*)(s + (z1w + y1w + x0c));

    float c00 = v00.x + (v00.y - v00.x) * wx;
    float c01 = v01.x + (v01.y - v01.x) * wx;
    float c10 = v10.x + (v10.y - v10.x) * wx;
    float c11 = v11.x + (v11.y - v11.x) * wx;
    float c0  = c00 + (c01 - c00) * wy;
    float c1  = c10 + (c11 - c10) * wy;
    float r   = c0 + (c1 - c0) * wz;

    float* dst = out + (size_t)((b * DD + z) * HH + y) * WW + x;
    __builtin_nontemporal_store(r, dst);
}

extern "C" void kernel_launch(void* const* d_in, const int* in_sizes, int n_in,
                              void* d_out, int out_size, void* d_ws, size_t ws_size,
                              hipStream_t stream) {
    const float* src = (const float*)d_in[0];
    const float* aff = (const float*)d_in[1];
    float* out = (float*)d_out;

    dim3 grid(HH / 2, DD, BB);   // 80 x 128 x 4 blocks, 256 threads each
    dim3 block(256);
    st_affine_kernel<<<grid, block, 0, stream>>>(src, aff, out);
}

// Round 4
// 29.997 us; speedup vs baseline: 1.9744x; 1.0157x over previous
//
#include <hip/hip_runtime.h>

#define DD 128
#define HH 160
#define WW 128
#define BB 4
#define HW  (HH * WW)
#define DHW (DD * HH * WW)

#define YB     (HH / 2)          // 80 y-pair blocks per z-slice
#define NWG    (YB * DD * BB)    // 40960 blocks
#define NXCD   8
#define CPX    (NWG / NXCD)      // 5120, exact (40960 % 8 == 0)

// 8-byte vector load with only 4-byte alignment guarantee.
typedef float f2 __attribute__((ext_vector_type(2), aligned(4)));

__global__ __launch_bounds__(256)
void st_affine_kernel(const float* __restrict__ src,
                      const float* __restrict__ aff,
                      float* __restrict__ out) {
    // XCD-aware bijective swizzle: consecutive hardware wgids round-robin
    // across the 8 XCDs; remap so each XCD gets a contiguous (b, z-band)
    // chunk in (y-pair fastest, z next, b slowest) order -> src-row reuse
    // between z/y-neighbor blocks becomes an L2 hit instead of an L3 refill.
    const int wgid = blockIdx.x;
    const int lin  = (wgid & (NXCD - 1)) * CPX + (wgid >> 3);

    const int yb = lin % YB;
    const int t  = lin / YB;
    const int z  = t & (DD - 1);
    const int b  = t >> 7;            // / DD (DD=128)

    const int tid = threadIdx.x;
    const int y   = yb * 2 + (tid >> 7);
    const int x   = tid & 127;        // lanes stride-1 in x

    const float* A = aff + b * 12;    // b uniform -> scalar loads
    const float cD = (float)DD / (float)(DD - 1);
    const float cH = (float)HH / (float)(HH - 1);
    const float cW = (float)WW / (float)(WW - 1);

    const float fz = (float)z, fy = (float)y, fx = (float)x;

    // loc = A @ [z,y,x,1];  i = loc * S/(S-1) - 0.5
    float lz = fmaf(A[0], fz, fmaf(A[1], fy, fmaf(A[2],  fx, A[3])));
    float ly = fmaf(A[4], fz, fmaf(A[5], fy, fmaf(A[6],  fx, A[7])));
    float lx = fmaf(A[8], fz, fmaf(A[9], fy, fmaf(A[10], fx, A[11])));

    float iz = fmaf(lz, cD, -0.5f);
    float iy = fmaf(ly, cH, -0.5f);
    float ix = fmaf(lx, cW, -0.5f);

    // border clamp
    ix = fminf(fmaxf(ix, 0.0f), (float)(WW - 1));
    iy = fminf(fmaxf(iy, 0.0f), (float)(HH - 1));
    iz = fminf(fmaxf(iz, 0.0f), (float)(DD - 1));

    float x0f = floorf(ix), y0f = floorf(iy), z0f = floorf(iz);
    float wy = iy - y0f, wz = iz - z0f;

    int x0 = (int)x0f, y0 = (int)y0f, z0 = (int)z0f;
    // shift base so [x0c, x0c+1] is always in-row; fold the clamp into wx.
    int x0c = min(x0, WW - 2);
    float wx = (ix - x0f) + (float)(x0 - x0c);

    int y1 = min(y0 + 1, HH - 1);
    int z1 = min(z0 + 1, DD - 1);

    const float* s = src + b * DHW;
    int z0w = z0 * HW, z1w = z1 * HW;
    int y0w = y0 << 7, y1w = y1 << 7;   // * WW (=128)

    f2 v00 = *(const f2*)(s + (z0w + y0w + x0c));
    f2 v01 = *(const f2*)(s + (z0w + y1w + x0c));
    f2 v10 = *(const f2*)(s + (z1w + y0w + x0c));
    f2 v11 = *(const f2*)(s + (z1w + y1w + x0c));

    float c00 = v00.x + (v00.y - v00.x) * wx;
    float c01 = v01.x + (v01.y - v01.x) * wx;
    float c10 = v10.x + (v10.y - v10.x) * wx;
    float c11 = v11.x + (v11.y - v11.x) * wx;
    float c0  = c00 + (c01 - c00) * wy;
    float c1  = c10 + (c11 - c10) * wy;
    float r   = c0 + (c1 - c0) * wz;

    float* dst = out + (size_t)((b * DD + z) * HH + y) * WW + x;
    __builtin_nontemporal_store(r, dst);
}

extern "C" void kernel_launch(void* const* d_in, const int* in_sizes, int n_in,
                              void* d_out, int out_size, void* d_ws, size_t ws_size,
                              hipStream_t stream) {
    const float* src = (const float*)d_in[0];
    const float* aff = (const float*)d_in[1];
    float* out = (float*)d_out;

    st_affine_kernel<<<dim3(NWG), dim3(256), 0, stream>>>(src, aff, out);
}

// Round 5
// 29.881 us; speedup vs baseline: 1.9821x; 1.0039x over previous
//
#include <hip/hip_runtime.h>

#define DD 128
#define HH 160
#define WW 128
#define BB 4
#define HW  (HH * WW)            // 20480
#define DHW (DD * HW)

#define YB4  (HH / 4)            // 40 blocks of 4 rows per z-slice
#define NWG  (YB4 * DD * BB)     // 20480 blocks
#define NXCD 8
#define CPX  (NWG / NXCD)        // 2560, exact

// 8-byte gather load, only 4-byte alignment guaranteed.
typedef float f2 __attribute__((ext_vector_type(2), aligned(4)));
// packed-math pair: element 0 = output row y, element 1 = output row y+1
typedef float v2 __attribute__((ext_vector_type(2)));

__global__ __launch_bounds__(256)
void st_affine_kernel(const float* __restrict__ src,
                      const float* __restrict__ aff,
                      float* __restrict__ out) {
    // XCD-aware bijective swizzle (keeps src reuse inside one XCD's L2)
    const int wgid = blockIdx.x;
    const int lin  = (wgid & (NXCD - 1)) * CPX + (wgid >> 3);

    const int yb = lin % YB4;
    const int t  = lin / YB4;
    const int z  = t & (DD - 1);
    const int b  = t >> 7;              // / DD

    const int tid = threadIdx.x;
    const int x   = tid & 127;          // lanes stride-1 in x
    const int y   = yb * 4 + (tid >> 7) * 2;   // this thread: rows y, y+1

    const float* A = aff + b * 12;      // b uniform -> scalar loads
    const float cD = (float)DD / (float)(DD - 1);
    const float cH = (float)HH / (float)(HH - 1);
    const float cW = (float)WW / (float)(WW - 1);

    const float fx = (float)x, fy = (float)y, fz = (float)z;

    // affine for row y; row y+1 = +A[col 1]
    float lz = fmaf(A[0], fz, fmaf(A[1], fy, fmaf(A[2],  fx, A[3])));
    float ly = fmaf(A[4], fz, fmaf(A[5], fy, fmaf(A[6],  fx, A[7])));
    float lx = fmaf(A[8], fz, fmaf(A[9], fy, fmaf(A[10], fx, A[11])));

    v2 lzv = {lz, lz + A[1]};
    v2 lyv = {ly, ly + A[5]};
    v2 lxv = {lx, lx + A[9]};

    // i = loc * S/(S-1) - 0.5  (algebraic reduction; packed fma)
    v2 izv = lzv * cD - 0.5f;
    v2 iyv = lyv * cH - 0.5f;
    v2 ixv = lxv * cW - 0.5f;

    // border clamp (med3)
    v2 izc, iyc, ixc;
    izc.x = __builtin_amdgcn_fmed3f(izv.x, 0.0f, (float)(DD - 1));
    izc.y = __builtin_amdgcn_fmed3f(izv.y, 0.0f, (float)(DD - 1));
    iyc.x = __builtin_amdgcn_fmed3f(iyv.x, 0.0f, (float)(HH - 1));
    iyc.y = __builtin_amdgcn_fmed3f(iyv.y, 0.0f, (float)(HH - 1));
    ixc.x = __builtin_amdgcn_fmed3f(ixv.x, 0.0f, (float)(WW - 1));
    ixc.y = __builtin_amdgcn_fmed3f(ixv.y, 0.0f, (float)(WW - 1));

    // base-shift clamp fold: base = min(floor(i), S-2); w = i_clamped - base.
    // At the top border (i == S-1): base = S-2, w = 1.0 -> exactly v[S-1].
    v2 z0f = {floorf(izc.x), floorf(izc.y)};
    v2 y0f = {floorf(iyc.x), floorf(iyc.y)};
    v2 x0f = {floorf(ixc.x), floorf(ixc.y)};
    v2 z0c = {fminf(z0f.x, (float)(DD - 2)), fminf(z0f.y, (float)(DD - 2))};
    v2 y0c = {fminf(y0f.x, (float)(HH - 2)), fminf(y0f.y, (float)(HH - 2))};
    v2 x0c = {fminf(x0f.x, (float)(WW - 2)), fminf(x0f.y, (float)(WW - 2))};
    v2 wz = izc - z0c;
    v2 wy = iyc - y0c;
    v2 wx = ixc - x0c;

    // linear element offset, exact in fp32 (max 2.62e6 < 2^23); packed fma
    v2 offf = z0c * (float)HW + y0c * (float)WW + x0c;
    int off0 = (int)offf.x;
    int off1 = (int)offf.y;

    const float* s  = src + b * DHW;
    const float* p0 = s + off0;
    const float* p1 = s + off1;

    // output 0: 4 row-pair gathers (z0/z1 x y0/y1), offsets 0, +W, +HW, +HW+W
    f2 a00 = *(const f2*)(p0);
    f2 a01 = *(const f2*)(p0 + WW);
    f2 a10 = *(const f2*)(p0 + HW);
    f2 a11 = *(const f2*)(p0 + HW + WW);
    // output 1
    f2 b00 = *(const f2*)(p1);
    f2 b01 = *(const f2*)(p1 + WW);
    f2 b10 = *(const f2*)(p1 + HW);
    f2 b11 = *(const f2*)(p1 + HW + WW);

    // x-lerps (within each loaded pair)
    v2 c00 = {fmaf(a00.y - a00.x, wx.x, a00.x), fmaf(b00.y - b00.x, wx.y, b00.x)};
    v2 c01 = {fmaf(a01.y - a01.x, wx.x, a01.x), fmaf(b01.y - b01.x, wx.y, b01.x)};
    v2 c10 = {fmaf(a10.y - a10.x, wx.x, a10.x), fmaf(b10.y - b10.x, wx.y, b10.x)};
    v2 c11 = {fmaf(a11.y - a11.x, wx.x, a11.x), fmaf(b11.y - b11.x, wx.y, b11.x)};

    // y- and z-lerps, packed across the two outputs
    v2 c0 = c00 + (c01 - c00) * wy;
    v2 c1 = c10 + (c11 - c10) * wy;
    v2 r  = c0 + (c1 - c0) * wz;

    float* dst = out + (size_t)((b * DD + z) * HH + y) * WW + x;
    __builtin_nontemporal_store(r.x, dst);
    __builtin_nontemporal_store(r.y, dst + WW);   // row y+1, +512B imm
}

extern "C" void kernel_launch(void* const* d_in, const int* in_sizes, int n_in,
                              void* d_out, int out_size, void* d_ws, size_t ws_size,
                              hipStream_t stream) {
    const float* src = (const float*)d_in[0];
    const float* aff = (const float*)d_in[1];
    float* out = (float*)d_out;

    st_affine_kernel<<<dim3(NWG), dim3(256), 0, stream>>>(src, aff, out);
}